// Round 3
// 7773.177 us; speedup vs baseline: 1.0822x; 1.0822x over previous
//
#include <hip/hip_runtime.h>

// Problem constants
#define LNUM 4
#define EDIM 1024
#define HID 1024
#define NH 16
#define HD 64
#define VOC 32000
#define SEQ 1024
#define BATCH 2
#define NTOK (BATCH * SEQ)   // 2048
#define HCHUNK 4             // heads per attention chunk (sT = 16 MB fp32)

typedef unsigned short u16;
typedef short bf16x8 __attribute__((ext_vector_type(8)));   // 8 bf16 in 4 VGPRs
typedef float f32x4 __attribute__((ext_vector_type(4)));

__device__ __forceinline__ u16 f2bf(float f) {
    union { float f; unsigned u; } c; c.f = f;
    return (u16)((c.u + 0x7fffu + ((c.u >> 16) & 1u)) >> 16);  // RNE
}

// -----------------------------------------------------------------------------
// bf16 MFMA GEMM, TN compute:
//   C[m,n] = scale * sum_k A(m,k)*B(n,k)  (+bias[n]) (+cadd[m,n]) (relu?)
// A: bf16 [M][K] row-major (K-contig).
// B: BT=false -> bf16 [N][K] row-major (K-contig).
//    BT=true  -> fp32 [K][N] row-major (n-contig, i.e. untransposed weights);
//                converted to bf16 + transposed into LDS on the fly.
// Outputs: Cf (fp32) and/or Cb (bf16), shared ldc / z-stride sC.
// Tile: 128 x BN, BK=32, 256 threads = 4 waves, mfma_f32_16x16x32_bf16.
// Requires M%128==0, N%BN==0, K%32==0. Batched over blockIdx.z.
// LDS rows padded to 40 shorts (80 B = 20 dwords; gcd(20,32)=4 spreads 16
// fragment rows across all 32 banks at worst 2-way => conflict-free per m136).
// -----------------------------------------------------------------------------
template <int BN, bool BT>
__global__ __launch_bounds__(256) void bgemm(
    const u16* __restrict__ Ag, const void* __restrict__ Bg,
    float* __restrict__ Cfg, u16* __restrict__ Cbg,
    int M, int N, int K, int lda, int ldb, int ldc,
    long sA, long sB, long sC, float scale,
    const float* __restrict__ bias, const float* __restrict__ cadd, int relu)
{
    constexpr int WAVES_N = BN / 64;        // 2 (BN=128) or 1 (BN=64)
    constexpr int WAVES_M = 4 / WAVES_N;    // 2 or 4
    constexpr int WTM = 128 / WAVES_M;      // 64 or 32 rows per wave
    constexpr int MF = WTM / 16;            // 4 or 2 m-fragments

    __shared__ u16 As[128][40];
    __shared__ u16 Bs[BN][40];

    const int tid = threadIdx.x;
    const int lane = tid & 63;
    const int w = tid >> 6;
    const int wr = (w / WAVES_N) * WTM;
    const int wc = (w % WAVES_N) * 64;
    const int fr = lane & 15;        // fragment row (A) / col (B)
    const int fk = (lane >> 4) * 8;  // fragment k offset (8 bf16)
    const int bm = blockIdx.y * 128;
    const int bn = blockIdx.x * BN;

    const u16* A = Ag + (long)blockIdx.z * sA;

    f32x4 acc[MF][4] = {};

    for (int k0 = 0; k0 < K; k0 += 32) {
        // ---- stage A tile: 128 rows x 32 k (4 chunks of 8 bf16) ----
        #pragma unroll
        for (int p = 0; p < 2; ++p) {
            int idx = p * 256 + tid;
            int r = idx >> 2, c = idx & 3;
            *reinterpret_cast<float4*>(&As[r][c * 8]) =
                *reinterpret_cast<const float4*>(&A[(long)(bm + r) * lda + k0 + c * 8]);
        }
        // ---- stage B tile ----
        if constexpr (!BT) {
            const u16* B = (const u16*)Bg + (long)blockIdx.z * sB;
            #pragma unroll
            for (int p = 0; p < BN * 4 / 256; ++p) {
                int idx = p * 256 + tid;
                int r = idx >> 2, c = idx & 3;
                *reinterpret_cast<float4*>(&Bs[r][c * 8]) =
                    *reinterpret_cast<const float4*>(&B[(long)(bn + r) * ldb + k0 + c * 8]);
            }
        } else {
            const float* B = (const float*)Bg + (long)blockIdx.z * sB;
            #pragma unroll
            for (int p = 0; p < BN * 16 / 256; ++p) {  // BN cols x 16 k-pairs
                int idx = p * 256 + tid;
                int n = idx & (BN - 1), kp = idx >> (BN == 128 ? 7 : 6);
                float lo = B[(long)(k0 + 2 * kp) * ldb + bn + n];
                float hi = B[(long)(k0 + 2 * kp + 1) * ldb + bn + n];
                unsigned pk = (unsigned)f2bf(lo) | ((unsigned)f2bf(hi) << 16);
                *reinterpret_cast<unsigned*>(&Bs[n][kp * 2]) = pk;
            }
        }
        __syncthreads();

        bf16x8 a[MF], b[4];
        #pragma unroll
        for (int i = 0; i < MF; ++i)
            a[i] = *reinterpret_cast<const bf16x8*>(&As[wr + i * 16 + fr][fk]);
        #pragma unroll
        for (int j = 0; j < 4; ++j)
            b[j] = *reinterpret_cast<const bf16x8*>(&Bs[wc + j * 16 + fr][fk]);
        #pragma unroll
        for (int i = 0; i < MF; ++i)
            #pragma unroll
            for (int j = 0; j < 4; ++j)
                acc[i][j] = __builtin_amdgcn_mfma_f32_16x16x32_bf16(a[i], b[j], acc[i][j], 0, 0, 0);
        __syncthreads();
    }

    float* Cf = Cfg ? Cfg + (long)blockIdx.z * sC : nullptr;
    u16*   Cb = Cbg ? Cbg + (long)blockIdx.z * sC : nullptr;
    const int cr = (lane >> 4) * 4;
    #pragma unroll
    for (int i = 0; i < MF; ++i) {
        #pragma unroll
        for (int j = 0; j < 4; ++j) {
            int col = bn + wc + j * 16 + (lane & 15);
            #pragma unroll
            for (int r = 0; r < 4; ++r) {
                int row = bm + wr + i * 16 + cr + r;
                float v = acc[i][j][r] * scale;
                if (bias) v += bias[col];
                if (cadd) v += cadd[(long)row * ldc + col];
                if (relu) v = fmaxf(v, 0.0f);
                long o = (long)row * ldc + col;
                if (Cf) Cf[o] = v;
                if (Cb) Cb[o] = f2bf(v);
            }
        }
    }
}

// per-batch bf16 transpose: out[b][d][s] = in[b][s][d]
__global__ __launch_bounds__(256) void vtrans_k(
    const u16* __restrict__ in, u16* __restrict__ out)
{
    __shared__ u16 t[32][33];
    int tx = threadIdx.x & 31, ty = threadIdx.x >> 5;  // ty in 0..7
    int s0 = blockIdx.x * 32, d0 = blockIdx.y * 32;
    const u16* ib = in + (long)blockIdx.z * SEQ * HID;
    u16* ob = out + (long)blockIdx.z * HID * SEQ;
    #pragma unroll
    for (int i = 0; i < 32; i += 8)
        t[ty + i][tx] = ib[(long)(s0 + ty + i) * HID + d0 + tx];
    __syncthreads();
    #pragma unroll
    for (int i = 0; i < 32; i += 8)
        ob[(long)(d0 + ty + i) * SEQ + s0 + tx] = t[tx][ty + i];
}

// x[b,s,e] = tok_embed[tokens[b,s], e] + pos_embed[s, e]; fp32 + bf16 copies
__global__ __launch_bounds__(256) void embed_k(
    const int* __restrict__ tokens, const float* __restrict__ tok_embed,
    const float* __restrict__ pos_embed, float* __restrict__ x, u16* __restrict__ xb)
{
    long i = (long)blockIdx.x * 256 + threadIdx.x;
    long se = i / EDIM;
    int e = (int)(i % EDIM);
    int s = (int)(se % SEQ);
    int t = tokens[se];
    float v = tok_embed[(long)t * EDIM + e] + pos_embed[(long)s * EDIM + e];
    x[i] = v;
    xb[i] = f2bf(v);
}

// column softmax on scoresT[h][t][s]: softmax over t for each (h,s) column.
// Coalesced (lane = column), online max+sum. Writes bf16 probsT. UNMASKED (bug-faithful).
__global__ __launch_bounds__(256) void colsoftmax_k(
    const float* __restrict__ sT, u16* __restrict__ pT)
{
    int s = blockIdx.x * 256 + threadIdx.x;
    const float* p = sT + (long)blockIdx.y * SEQ * SEQ;
    u16* o = pT + (long)blockIdx.y * SEQ * SEQ;
    float m = -1e30f, sum = 0.0f;
    for (int t = 0; t < SEQ; ++t) {
        float v = p[(long)t * SEQ + s];
        float nm = fmaxf(m, v);
        sum = sum * __expf(m - nm) + __expf(v - nm);
        m = nm;
    }
    float inv = 1.0f / sum;
    for (int t = 0; t < SEQ; ++t)
        o[(long)t * SEQ + s] = f2bf(__expf(p[(long)t * SEQ + s] - m) * inv);
}

// out(bf16) = rmsnorm(xin (+ add)) * scale ; add may be null
__global__ __launch_bounds__(256) void rmsnorm_k(
    const float* __restrict__ xin, const float* __restrict__ add,
    const float* __restrict__ scale, u16* __restrict__ out, int ncol)
{
    long row = blockIdx.x;
    const float* a = xin + row * (long)ncol;
    const float* b = add ? add + row * (long)ncol : nullptr;
    u16* o = out + row * (long)ncol;
    int tid = threadIdx.x;
    __shared__ float red[256];

    float ss = 0.0f;
    for (int c = tid; c < ncol; c += 256) { float v = a[c] + (b ? b[c] : 0.0f); ss += v * v; }
    red[tid] = ss; __syncthreads();
    for (int s = 128; s > 0; s >>= 1) { if (tid < s) red[tid] += red[tid + s]; __syncthreads(); }
    float r = rsqrtf(red[0] / (float)ncol + 1e-6f);
    for (int c = tid; c < ncol; c += 256) {
        float v = a[c] + (b ? b[c] : 0.0f);
        o[c] = f2bf(v * r * scale[c]);
    }
}

// in-place log_softmax on fp32 rows
__global__ __launch_bounds__(256) void logsoftmax_k(float* __restrict__ out, int ncol)
{
    long row = blockIdx.x;
    float* p = out + row * (long)ncol;
    int tid = threadIdx.x;
    __shared__ float red[256];

    float lmax = -1e30f;
    for (int c = tid; c < ncol; c += 256) lmax = fmaxf(lmax, p[c]);
    red[tid] = lmax; __syncthreads();
    for (int s = 128; s > 0; s >>= 1) { if (tid < s) red[tid] = fmaxf(red[tid], red[tid + s]); __syncthreads(); }
    float m = red[0]; __syncthreads();

    float lsum = 0.0f;
    for (int c = tid; c < ncol; c += 256) lsum += expf(p[c] - m);
    red[tid] = lsum; __syncthreads();
    for (int s = 128; s > 0; s >>= 1) { if (tid < s) red[tid] += red[tid + s]; __syncthreads(); }
    float lse = m + logf(red[0]);
    for (int c = tid; c < ncol; c += 256) p[c] = p[c] - lse;
}

extern "C" void kernel_launch(void* const* d_in, const int* in_sizes, int n_in,
                              void* d_out, int out_size, void* d_ws, size_t ws_size,
                              hipStream_t stream)
{
    const int*   tokens     = (const int*)d_in[0];
    const float* tok_embed  = (const float*)d_in[1];
    const float* pos_embed  = (const float*)d_in[2];
    const float* Qw_all     = (const float*)d_in[3];
    const float* Kw_all     = (const float*)d_in[4];
    const float* Vw_all     = (const float*)d_in[5];
    const float* Ow_all     = (const float*)d_in[6];
    const float* rms2_all   = (const float*)d_in[7];
    const float* w1_all     = (const float*)d_in[8];
    const float* b1_all     = (const float*)d_in[9];
    const float* w2_all     = (const float*)d_in[10];
    const float* b2_all     = (const float*)d_in[11];
    const float* final_rms  = (const float*)d_in[12];
    const float* w_out      = (const float*)d_in[13];
    const float* b_out      = (const float*)d_in[14];
    float* out = (float*)d_out;

    // workspace layout — 60 MB total (previous session proved >=80 MB available)
    if (ws_size < ((size_t)60 << 20)) return;   // graceful fail -> diagnostics survive
    char* W = (char*)d_ws;
    float* x    = (float*)(W + ((long)0  << 20));   // 8 MB  fp32 residual
    float* proj = (float*)(W + ((long)8  << 20));   // 8 MB  fp32; pT aliases (disjoint lifetime)
    u16* xb   = (u16*)(W + ((long)16 << 20));       // 4 MB  bf16 copy of x
    u16* q    = (u16*)(W + ((long)20 << 20));       // 4 MB
    u16* kk   = (u16*)(W + ((long)24 << 20));       // 4 MB
    u16* vt   = (u16*)(W + ((long)28 << 20));       // 4 MB  v transposed [b][hid][s]
    u16* mha  = (u16*)(W + ((long)32 << 20));       // 4 MB
    u16* rn   = (u16*)(W + ((long)36 << 20));       // 4 MB
    u16* ffh  = (u16*)(W + ((long)40 << 20));       // 16 MB FFN hidden; sT aliases
    u16* vv   = (u16*)(W + ((long)56 << 20));       // 4 MB  v un-transposed [b][s][hid]
    float* sT = (float*)ffh;                        // 16 MB scoresT chunk (4 heads, fp32)
    u16* pT   = (u16*)proj;                         // 8 MB probsT chunk (4 heads, bf16)

    // 1) embedding (fp32 + bf16)
    embed_k<<<(NTOK * (long)EDIM) / 256, 256, 0, stream>>>(tokens, tok_embed, pos_embed, x, xb);

    for (int l = 0; l < LNUM; ++l) {
        const float* Qw  = Qw_all + (long)l * EDIM * HID;
        const float* Kw  = Kw_all + (long)l * EDIM * HID;
        const float* Vw  = Vw_all + (long)l * EDIM * HID;
        const float* Ow  = Ow_all + (long)l * HID * EDIM;
        const float* rs2 = rms2_all + (long)l * EDIM;
        const float* w1  = w1_all + (long)l * EDIM * 4 * EDIM;
        const float* b1  = b1_all + (long)l * 4 * EDIM;
        const float* w2  = w2_all + (long)l * 4 * EDIM * EDIM;
        const float* b2  = b2_all + (long)l * EDIM;

        // q/k/v projections (fp32 weights converted inside the GEMM)
        bgemm<128, true><<<dim3(HID / 128, NTOK / 128, 1), 256, 0, stream>>>(
            xb, Qw, nullptr, q, NTOK, HID, EDIM, EDIM, HID, HID, 0, 0, 0, 1.0f, nullptr, nullptr, 0);
        bgemm<128, true><<<dim3(HID / 128, NTOK / 128, 1), 256, 0, stream>>>(
            xb, Kw, nullptr, kk, NTOK, HID, EDIM, EDIM, HID, HID, 0, 0, 0, 1.0f, nullptr, nullptr, 0);
        bgemm<128, true><<<dim3(HID / 128, NTOK / 128, 1), 256, 0, stream>>>(
            xb, Vw, nullptr, vv, NTOK, HID, EDIM, EDIM, HID, HID, 0, 0, 0, 1.0f, nullptr, nullptr, 0);
        // vt[b][d][s] = vv[b][s][d]
        vtrans_k<<<dim3(SEQ / 32, HID / 32, BATCH), 256, 0, stream>>>(vv, vt);

        for (int b = 0; b < BATCH; ++b) {
            const u16* qb = q  + (long)b * SEQ * HID;
            const u16* kb = kk + (long)b * SEQ * HID;
            for (int h0 = 0; h0 < NH; h0 += HCHUNK) {
                // scoresT[h][t][s] = 0.125 * k_t . q_s  (z over heads)
                bgemm<128, false><<<dim3(SEQ / 128, SEQ / 128, HCHUNK), 256, 0, stream>>>(
                    kb + h0 * HD, qb + h0 * HD, sT, nullptr, SEQ, SEQ, HD, HID, HID, SEQ,
                    HD, HD, (long)SEQ * SEQ, 0.125f, nullptr, nullptr, 0);
                // softmax over t (columns of scoresT) -> bf16 probsT
                colsoftmax_k<<<dim3(SEQ / 256, HCHUNK), 256, 0, stream>>>(sT, pT);
                // mha[t][(h0+h)*HD+d] = sum_s probsT[h][t][s] * vt[b][(h0+h)*HD+d][s]
                bgemm<64, false><<<dim3(1, SEQ / 128, HCHUNK), 256, 0, stream>>>(
                    pT, vt + (long)b * HID * SEQ + (long)h0 * HD * SEQ, nullptr,
                    mha + (long)b * SEQ * HID + h0 * HD,
                    SEQ, HD, SEQ, SEQ, SEQ, HID,
                    (long)SEQ * SEQ, (long)HD * SEQ, HD, 1.0f, nullptr, nullptr, 0);
            }
        }

        // proj = mha @ Ow  (fp32 out)
        bgemm<128, true><<<dim3(EDIM / 128, NTOK / 128, 1), 256, 0, stream>>>(
            mha, Ow, proj, nullptr, NTOK, EDIM, HID, HID, EDIM, EDIM, 0, 0, 0, 1.0f, nullptr, nullptr, 0);

        // rn = bf16(rmsnorm(x + proj) * rs2)
        rmsnorm_k<<<NTOK, 256, 0, stream>>>(x, proj, rs2, rn, EDIM);

        // ffh = bf16(relu(rn @ w1 + b1))
        bgemm<128, true><<<dim3(4 * EDIM / 128, NTOK / 128, 1), 256, 0, stream>>>(
            rn, w1, nullptr, ffh, NTOK, 4 * EDIM, EDIM, EDIM, 4 * EDIM, 4 * EDIM,
            0, 0, 0, 1.0f, b1, nullptr, 1);

        // x = ffh @ w2 + b2 + proj  (fp32 x AND bf16 xb; input x NOT re-added — bug-faithful)
        bgemm<128, true><<<dim3(EDIM / 128, NTOK / 128, 1), 256, 0, stream>>>(
            ffh, w2, x, xb, NTOK, EDIM, 4 * EDIM, 4 * EDIM, EDIM, EDIM,
            0, 0, 0, 1.0f, b2, proj, 0);
    }

    // final rmsnorm -> bf16
    rmsnorm_k<<<NTOK, 256, 0, stream>>>(x, nullptr, final_rms, rn, EDIM);

    // logits = rn @ w_out + b_out  (fp32 into d_out)
    bgemm<128, true><<<dim3(VOC / 128, NTOK / 128, 1), 256, 0, stream>>>(
        rn, w_out, out, nullptr, NTOK, VOC, EDIM, EDIM, VOC, VOC,
        0, 0, 0, 1.0f, b_out, nullptr, 0);

    logsoftmax_k<<<NTOK, 256, 0, stream>>>(out, VOC);
}

// Round 4
// 5957.302 us; speedup vs baseline: 1.4120x; 1.3048x over previous
//
#include <hip/hip_runtime.h>

// Problem constants
#define LNUM 4
#define EDIM 1024
#define HID 1024
#define NH 16
#define HD 64
#define VOC 32000
#define SEQ 1024
#define BATCH 2
#define NTOK (BATCH * SEQ)   // 2048
#define HCHUNK 4             // heads per attention chunk (sT = 16 MB fp32)
#define TC 8                 // t-chunks for 2-phase column softmax

typedef unsigned short u16;
typedef short bf16x8 __attribute__((ext_vector_type(8)));   // 8 bf16 in 4 VGPRs
typedef float f32x4 __attribute__((ext_vector_type(4)));

__device__ __forceinline__ u16 f2bf(float f) {
    union { float f; unsigned u; } c; c.f = f;
    return (u16)((c.u + 0x7fffu + ((c.u >> 16) & 1u)) >> 16);  // RNE
}

// -----------------------------------------------------------------------------
// bf16 MFMA GEMM, TN compute:
//   C[m,n] = scale * sum_k A(m,k)*B(n,k)  (+bias[n]) (+cadd[m,n]) (relu?)
// A: bf16 [M][K] row-major (K-contig).
// B: BT=false -> bf16 [N][K] row-major (K-contig).
//    BT=true  -> fp32 [K][N] row-major (untransposed weights), converted to
//                bf16 + transposed into LDS on the fly.
// Outputs: Cf (fp32) and/or Cb (bf16), shared ldc / z-stride sC.
// Tile: BM x BN, BK=32, 256 threads = 4 waves, mfma_f32_16x16x32_bf16.
// Supported: (BM,BN) = (128,128), (128,64), (64,64).
// Block remap: bijective XCD chunking + m-fastest order within chunk, so the
// m-blocks sharing one B-panel run consecutively on one XCD (L2 B-reuse).
// -----------------------------------------------------------------------------
template <int BM, int BN, bool BT>
__global__ __launch_bounds__(256) void bgemm(
    const u16* __restrict__ Ag, const void* __restrict__ Bg,
    float* __restrict__ Cfg, u16* __restrict__ Cbg,
    int M, int N, int K, int lda, int ldb, int ldc,
    long sA, long sB, long sC, float scale,
    const float* __restrict__ bias, const float* __restrict__ cadd, int relu)
{
    constexpr int WAVES_N = BN / 64;        // 2 (BN=128) or 1 (BN=64)
    constexpr int WAVES_M = 4 / WAVES_N;    // 2 or 4
    constexpr int WTM = BM / WAVES_M;       // 64 (128,128) / 32 (128,64) / 16 (64,64)
    constexpr int MF = WTM / 16;            // 4 / 2 / 1

    __shared__ u16 As[BM][40];
    __shared__ u16 Bs[BN][40];

    const int tid = threadIdx.x;
    const int lane = tid & 63;
    const int w = tid >> 6;
    const int wr = (w / WAVES_N) * WTM;
    const int wc = (w % WAVES_N) * 64;
    const int fr = lane & 15;        // fragment row (A) / col (B)
    const int fk = (lane >> 4) * 8;  // fragment k offset (8 bf16)

    // ---- bijective XCD-chunked, m-fastest block remap ----
    const int nwg = gridDim.x * gridDim.y;
    const int lin = blockIdx.y * gridDim.x + blockIdx.x;
    const int q8 = nwg >> 3, r8 = nwg & 7;
    const int xcd = lin & 7, pos = lin >> 3;
    const int wg = (xcd < r8 ? xcd * (q8 + 1) : r8 * (q8 + 1) + (xcd - r8) * q8) + pos;
    const int MB = gridDim.y;                 // number of m-blocks
    const int bm = (wg % MB) * BM;
    const int bn = (wg / MB) * BN;

    const u16* A = Ag + (long)blockIdx.z * sA;

    f32x4 acc[MF][4] = {};

    for (int k0 = 0; k0 < K; k0 += 32) {
        // ---- stage A tile: BM rows x 32 k (4 chunks of 8 bf16) ----
        #pragma unroll
        for (int p = 0; p < BM / 64; ++p) {
            int idx = p * 256 + tid;
            int r = idx >> 2, c = idx & 3;
            *reinterpret_cast<float4*>(&As[r][c * 8]) =
                *reinterpret_cast<const float4*>(&A[(long)(bm + r) * lda + k0 + c * 8]);
        }
        // ---- stage B tile ----
        if constexpr (!BT) {
            const u16* B = (const u16*)Bg + (long)blockIdx.z * sB;
            #pragma unroll
            for (int p = 0; p < BN / 64; ++p) {
                int idx = p * 256 + tid;
                int r = idx >> 2, c = idx & 3;
                *reinterpret_cast<float4*>(&Bs[r][c * 8]) =
                    *reinterpret_cast<const float4*>(&B[(long)(bn + r) * ldb + k0 + c * 8]);
            }
        } else {
            const float* B = (const float*)Bg + (long)blockIdx.z * sB;
            #pragma unroll
            for (int p = 0; p < BN / 16; ++p) {  // BN cols x 16 k-pairs
                int idx = p * 256 + tid;
                int n = idx & (BN - 1), kp = idx >> (BN == 128 ? 7 : 6);
                float lo = B[(long)(k0 + 2 * kp) * ldb + bn + n];
                float hi = B[(long)(k0 + 2 * kp + 1) * ldb + bn + n];
                unsigned pk = (unsigned)f2bf(lo) | ((unsigned)f2bf(hi) << 16);
                *reinterpret_cast<unsigned*>(&Bs[n][kp * 2]) = pk;
            }
        }
        __syncthreads();

        bf16x8 a[MF], b[4];
        #pragma unroll
        for (int i = 0; i < MF; ++i)
            a[i] = *reinterpret_cast<const bf16x8*>(&As[wr + i * 16 + fr][fk]);
        #pragma unroll
        for (int j = 0; j < 4; ++j)
            b[j] = *reinterpret_cast<const bf16x8*>(&Bs[wc + j * 16 + fr][fk]);
        #pragma unroll
        for (int i = 0; i < MF; ++i)
            #pragma unroll
            for (int j = 0; j < 4; ++j)
                acc[i][j] = __builtin_amdgcn_mfma_f32_16x16x32_bf16(a[i], b[j], acc[i][j], 0, 0, 0);
        __syncthreads();
    }

    float* Cf = Cfg ? Cfg + (long)blockIdx.z * sC : nullptr;
    u16*   Cb = Cbg ? Cbg + (long)blockIdx.z * sC : nullptr;
    const int cr = (lane >> 4) * 4;
    #pragma unroll
    for (int i = 0; i < MF; ++i) {
        #pragma unroll
        for (int j = 0; j < 4; ++j) {
            int col = bn + wc + j * 16 + (lane & 15);
            #pragma unroll
            for (int r = 0; r < 4; ++r) {
                int row = bm + wr + i * 16 + cr + r;
                float v = acc[i][j][r] * scale;
                if (bias) v += bias[col];
                if (cadd) v += cadd[(long)row * ldc + col];
                if (relu) v = fmaxf(v, 0.0f);
                long o = (long)row * ldc + col;
                if (Cf) Cf[o] = v;
                if (Cb) Cb[o] = f2bf(v);
            }
        }
    }
}

// per-batch bf16 transpose: out[b][d][s] = in[b][s][d]
__global__ __launch_bounds__(256) void vtrans_k(
    const u16* __restrict__ in, u16* __restrict__ out)
{
    __shared__ u16 t[32][33];
    int tx = threadIdx.x & 31, ty = threadIdx.x >> 5;  // ty in 0..7
    int s0 = blockIdx.x * 32, d0 = blockIdx.y * 32;
    const u16* ib = in + (long)blockIdx.z * SEQ * HID;
    u16* ob = out + (long)blockIdx.z * HID * SEQ;
    #pragma unroll
    for (int i = 0; i < 32; i += 8)
        t[ty + i][tx] = ib[(long)(s0 + ty + i) * HID + d0 + tx];
    __syncthreads();
    #pragma unroll
    for (int i = 0; i < 32; i += 8)
        ob[(long)(d0 + ty + i) * SEQ + s0 + tx] = t[tx][ty + i];
}

// x[b,s,e] = tok_embed[tokens[b,s], e] + pos_embed[s, e]; fp32 + bf16 copies
__global__ __launch_bounds__(256) void embed_k(
    const int* __restrict__ tokens, const float* __restrict__ tok_embed,
    const float* __restrict__ pos_embed, float* __restrict__ x, u16* __restrict__ xb)
{
    long i = (long)blockIdx.x * 256 + threadIdx.x;
    long se = i / EDIM;
    int e = (int)(i % EDIM);
    int s = (int)(se % SEQ);
    int t = tokens[se];
    float v = tok_embed[(long)t * EDIM + e] + pos_embed[(long)s * EDIM + e];
    x[i] = v;
    xb[i] = f2bf(v);
}

// ---- 2-phase column softmax over t for scoresT[h][t][s] (UNMASKED, bug-faithful) ----
// phase 1: per (h, t-chunk, s) online max/sum partials.
// grid (SEQ/256, TC, HCHUNK); stats[h][tc][{m,sum}][s]
__global__ __launch_bounds__(256) void colsm_stats(
    const float* __restrict__ sT, float* __restrict__ stats)
{
    int s = blockIdx.x * 256 + threadIdx.x;
    int tc = blockIdx.y, h = blockIdx.z;
    const float* p = sT + (long)h * SEQ * SEQ;
    float m = -1e30f, sum = 0.0f;
    for (int t = tc * (SEQ / TC); t < (tc + 1) * (SEQ / TC); ++t) {
        float v = p[(long)t * SEQ + s];
        float nm = fmaxf(m, v);
        sum = sum * __expf(m - nm) + __expf(v - nm);
        m = nm;
    }
    float* st = stats + (long)(h * TC + tc) * 2 * SEQ;
    st[s] = m;
    st[SEQ + s] = sum;
}

// phase 2: combine TC partials per column, then write bf16 probs for own t-chunk.
__global__ __launch_bounds__(256) void colsm_write(
    const float* __restrict__ sT, const float* __restrict__ stats,
    u16* __restrict__ pT)
{
    int s = blockIdx.x * 256 + threadIdx.x;
    int tc = blockIdx.y, h = blockIdx.z;
    float m = -1e30f, sum = 0.0f;
    for (int c = 0; c < TC; ++c) {
        const float* st = stats + (long)(h * TC + c) * 2 * SEQ;
        float mc = st[s], sc = st[SEQ + s];
        float nm = fmaxf(m, mc);
        sum = sum * __expf(m - nm) + sc * __expf(mc - nm);
        m = nm;
    }
    float inv = 1.0f / sum;
    const float* p = sT + (long)h * SEQ * SEQ;
    u16* o = pT + (long)h * SEQ * SEQ;
    for (int t = tc * (SEQ / TC); t < (tc + 1) * (SEQ / TC); ++t)
        o[(long)t * SEQ + s] = f2bf(__expf(p[(long)t * SEQ + s] - m) * inv);
}

// out(bf16) = rmsnorm(xin (+ add)) * scale ; add may be null
__global__ __launch_bounds__(256) void rmsnorm_k(
    const float* __restrict__ xin, const float* __restrict__ add,
    const float* __restrict__ scale, u16* __restrict__ out, int ncol)
{
    long row = blockIdx.x;
    const float* a = xin + row * (long)ncol;
    const float* b = add ? add + row * (long)ncol : nullptr;
    u16* o = out + row * (long)ncol;
    int tid = threadIdx.x;
    __shared__ float red[256];

    float ss = 0.0f;
    for (int c = tid; c < ncol; c += 256) { float v = a[c] + (b ? b[c] : 0.0f); ss += v * v; }
    red[tid] = ss; __syncthreads();
    for (int s = 128; s > 0; s >>= 1) { if (tid < s) red[tid] += red[tid + s]; __syncthreads(); }
    float r = rsqrtf(red[0] / (float)ncol + 1e-6f);
    for (int c = tid; c < ncol; c += 256) {
        float v = a[c] + (b ? b[c] : 0.0f);
        o[c] = f2bf(v * r * scale[c]);
    }
}

// in-place log_softmax on fp32 rows
__global__ __launch_bounds__(256) void logsoftmax_k(float* __restrict__ out, int ncol)
{
    long row = blockIdx.x;
    float* p = out + row * (long)ncol;
    int tid = threadIdx.x;
    __shared__ float red[256];

    float lmax = -1e30f;
    for (int c = tid; c < ncol; c += 256) lmax = fmaxf(lmax, p[c]);
    red[tid] = lmax; __syncthreads();
    for (int s = 128; s > 0; s >>= 1) { if (tid < s) red[tid] = fmaxf(red[tid], red[tid + s]); __syncthreads(); }
    float m = red[0]; __syncthreads();

    float lsum = 0.0f;
    for (int c = tid; c < ncol; c += 256) lsum += expf(p[c] - m);
    red[tid] = lsum; __syncthreads();
    for (int s = 128; s > 0; s >>= 1) { if (tid < s) red[tid] += red[tid + s]; __syncthreads(); }
    float lse = m + logf(red[0]);
    for (int c = tid; c < ncol; c += 256) p[c] = p[c] - lse;
}

extern "C" void kernel_launch(void* const* d_in, const int* in_sizes, int n_in,
                              void* d_out, int out_size, void* d_ws, size_t ws_size,
                              hipStream_t stream)
{
    const int*   tokens     = (const int*)d_in[0];
    const float* tok_embed  = (const float*)d_in[1];
    const float* pos_embed  = (const float*)d_in[2];
    const float* Qw_all     = (const float*)d_in[3];
    const float* Kw_all     = (const float*)d_in[4];
    const float* Vw_all     = (const float*)d_in[5];
    const float* Ow_all     = (const float*)d_in[6];
    const float* rms2_all   = (const float*)d_in[7];
    const float* w1_all     = (const float*)d_in[8];
    const float* b1_all     = (const float*)d_in[9];
    const float* w2_all     = (const float*)d_in[10];
    const float* b2_all     = (const float*)d_in[11];
    const float* final_rms  = (const float*)d_in[12];
    const float* w_out      = (const float*)d_in[13];
    const float* b_out      = (const float*)d_in[14];
    float* out = (float*)d_out;

    // workspace layout — 60 MB total
    if (ws_size < ((size_t)60 << 20)) return;   // graceful fail -> diagnostics survive
    char* W = (char*)d_ws;
    float* x    = (float*)(W + ((long)0  << 20));   // 8 MB  fp32 residual
    float* proj = (float*)(W + ((long)8  << 20));   // 8 MB  fp32; pT aliases (disjoint lifetime)
    u16* xb   = (u16*)(W + ((long)16 << 20));       // 4 MB  bf16 copy of x
    u16* q    = (u16*)(W + ((long)20 << 20));       // 4 MB
    u16* kk   = (u16*)(W + ((long)24 << 20));       // 4 MB
    u16* vt   = (u16*)(W + ((long)28 << 20));       // 4 MB  v transposed [b][hid][s]
    u16* mha  = (u16*)(W + ((long)32 << 20));       // 4 MB
    u16* rn   = (u16*)(W + ((long)36 << 20));       // 4 MB
    u16* ffh  = (u16*)(W + ((long)40 << 20));       // 16 MB FFN hidden; sT aliases
    u16* vv   = (u16*)(W + ((long)56 << 20));       // 4 MB  v un-transposed; softmax stats alias
    float* sT = (float*)ffh;                        // 16 MB scoresT chunk (4 heads, fp32)
    u16* pT   = (u16*)proj;                         // 8 MB probsT chunk (4 heads, bf16)
    float* smstats = (float*)vv;                    // 256 KB softmax partials (vv dead then)

    // 1) embedding (fp32 + bf16)
    embed_k<<<(NTOK * (long)EDIM) / 256, 256, 0, stream>>>(tokens, tok_embed, pos_embed, x, xb);

    for (int l = 0; l < LNUM; ++l) {
        const float* Qw  = Qw_all + (long)l * EDIM * HID;
        const float* Kw  = Kw_all + (long)l * EDIM * HID;
        const float* Vw  = Vw_all + (long)l * EDIM * HID;
        const float* Ow  = Ow_all + (long)l * HID * EDIM;
        const float* rs2 = rms2_all + (long)l * EDIM;
        const float* w1  = w1_all + (long)l * EDIM * 4 * EDIM;
        const float* b1  = b1_all + (long)l * 4 * EDIM;
        const float* w2  = w2_all + (long)l * 4 * EDIM * EDIM;
        const float* b2  = b2_all + (long)l * EDIM;

        // q/k/v projections (fp32 weights converted inside the GEMM)
        bgemm<128, 128, true><<<dim3(HID / 128, NTOK / 128, 1), 256, 0, stream>>>(
            xb, Qw, nullptr, q, NTOK, HID, EDIM, EDIM, HID, HID, 0, 0, 0, 1.0f, nullptr, nullptr, 0);
        bgemm<128, 128, true><<<dim3(HID / 128, NTOK / 128, 1), 256, 0, stream>>>(
            xb, Kw, nullptr, kk, NTOK, HID, EDIM, EDIM, HID, HID, 0, 0, 0, 1.0f, nullptr, nullptr, 0);
        bgemm<128, 128, true><<<dim3(HID / 128, NTOK / 128, 1), 256, 0, stream>>>(
            xb, Vw, nullptr, vv, NTOK, HID, EDIM, EDIM, HID, HID, 0, 0, 0, 1.0f, nullptr, nullptr, 0);
        // vt[b][d][s] = vv[b][s][d]
        vtrans_k<<<dim3(SEQ / 32, HID / 32, BATCH), 256, 0, stream>>>(vv, vt);

        for (int b = 0; b < BATCH; ++b) {
            const u16* qb = q  + (long)b * SEQ * HID;
            const u16* kb = kk + (long)b * SEQ * HID;
            for (int h0 = 0; h0 < NH; h0 += HCHUNK) {
                // scoresT[h][t][s] = 0.125 * k_t . q_s  (z over heads)
                bgemm<128, 128, false><<<dim3(SEQ / 128, SEQ / 128, HCHUNK), 256, 0, stream>>>(
                    kb + h0 * HD, qb + h0 * HD, sT, nullptr, SEQ, SEQ, HD, HID, HID, SEQ,
                    HD, HD, (long)SEQ * SEQ, 0.125f, nullptr, nullptr, 0);
                // 2-phase column softmax -> bf16 probsT
                colsm_stats<<<dim3(SEQ / 256, TC, HCHUNK), 256, 0, stream>>>(sT, smstats);
                colsm_write<<<dim3(SEQ / 256, TC, HCHUNK), 256, 0, stream>>>(sT, smstats, pT);
                // mha[t][(h0+h)*HD+d] = sum_s probsT[h][t][s] * vt[b][(h0+h)*HD+d][s]
                bgemm<64, 64, false><<<dim3(1, SEQ / 64, HCHUNK), 256, 0, stream>>>(
                    pT, vt + (long)b * HID * SEQ + (long)h0 * HD * SEQ, nullptr,
                    mha + (long)b * SEQ * HID + h0 * HD,
                    SEQ, HD, SEQ, SEQ, SEQ, HID,
                    (long)SEQ * SEQ, (long)HD * SEQ, HD, 1.0f, nullptr, nullptr, 0);
            }
        }

        // proj = mha @ Ow  (fp32 out)
        bgemm<128, 128, true><<<dim3(EDIM / 128, NTOK / 128, 1), 256, 0, stream>>>(
            mha, Ow, proj, nullptr, NTOK, EDIM, HID, HID, EDIM, EDIM, 0, 0, 0, 1.0f, nullptr, nullptr, 0);

        // rn = bf16(rmsnorm(x + proj) * rs2)
        rmsnorm_k<<<NTOK, 256, 0, stream>>>(x, proj, rs2, rn, EDIM);

        // ffh = bf16(relu(rn @ w1 + b1))
        bgemm<128, 128, true><<<dim3(4 * EDIM / 128, NTOK / 128, 1), 256, 0, stream>>>(
            rn, w1, nullptr, ffh, NTOK, 4 * EDIM, EDIM, EDIM, 4 * EDIM, 4 * EDIM,
            0, 0, 0, 1.0f, b1, nullptr, 1);

        // x = ffh @ w2 + b2 + proj  (fp32 x AND bf16 xb; input x NOT re-added — bug-faithful)
        bgemm<128, 128, true><<<dim3(EDIM / 128, NTOK / 128, 1), 256, 0, stream>>>(
            ffh, w2, x, xb, NTOK, EDIM, 4 * EDIM, 4 * EDIM, EDIM, EDIM,
            0, 0, 0, 1.0f, b2, proj, 0);
    }

    // final rmsnorm -> bf16
    rmsnorm_k<<<NTOK, 256, 0, stream>>>(x, nullptr, final_rms, rn, EDIM);

    // logits = rn @ w_out + b_out  (fp32 into d_out)
    bgemm<128, 128, true><<<dim3(VOC / 128, NTOK / 128, 1), 256, 0, stream>>>(
        rn, w_out, out, nullptr, NTOK, VOC, EDIM, EDIM, VOC, VOC,
        0, 0, 0, 1.0f, b_out, nullptr, 0);

    logsoftmax_k<<<NTOK, 256, 0, stream>>>(out, VOC);
}

// Round 5
// 5381.436 us; speedup vs baseline: 1.5631x; 1.1070x over previous
//
#include <hip/hip_runtime.h>

// Problem constants
#define LNUM 4
#define EDIM 1024
#define HID 1024
#define NH 16
#define HD 64
#define VOC 32000
#define SEQ 1024
#define BATCH 2
#define NTOK (BATCH * SEQ)   // 2048
#define HCHUNK 4             // heads per attention chunk (sT = 16 MB fp32)
#define TC 8                 // t-chunks for 2-phase column softmax

typedef unsigned short u16;
typedef short bf16x8 __attribute__((ext_vector_type(8)));   // 8 bf16 in 4 VGPRs
typedef float f32x4 __attribute__((ext_vector_type(4)));

__device__ __forceinline__ u16 f2bf(float f) {
    union { float f; unsigned u; } c; c.f = f;
    return (u16)((c.u + 0x7fffu + ((c.u >> 16) & 1u)) >> 16);  // RNE
}

// -----------------------------------------------------------------------------
// bf16 MFMA GEMM, TN compute:
//   C[m,n] = scale * sum_k A(m,k)*B(n,k)  (+bias[n]) (+cadd[m,n]) (relu?)
// A: bf16 [M][K] row-major (K-contig, lda). B: bf16 [N][K] row-major (ldb).
// Outputs: Cf (fp32) and/or Cb (bf16), shared ldc / z-stride sC.
// Tile: BM x BN, BK=32, 256 threads = 4 waves, mfma_f32_16x16x32_bf16.
// Supported: (BM,BN) = (128,128), (64,64).
// LDS rows padded to 40 shorts (80 B): worst 2-way bank aliasing (free, m136).
// Block remap: bijective XCD chunking + m-fastest order (L2 B-panel reuse).
// -----------------------------------------------------------------------------
template <int BM, int BN>
__global__ __launch_bounds__(256) void bgemm(
    const u16* __restrict__ Ag, const u16* __restrict__ Bg,
    float* __restrict__ Cfg, u16* __restrict__ Cbg,
    int M, int N, int K, int lda, int ldb, int ldc,
    long sA, long sB, long sC, float scale,
    const float* __restrict__ bias, const float* __restrict__ cadd, int relu)
{
    constexpr int WAVES_N = BN / 64;        // 2 (BN=128) or 1 (BN=64)
    constexpr int WAVES_M = 4 / WAVES_N;    // 2 or 4
    constexpr int WTM = BM / WAVES_M;       // 64 (128,128) / 16 (64,64)
    constexpr int MF = WTM / 16;            // 4 / 1

    __shared__ u16 As[BM][40];
    __shared__ u16 Bs[BN][40];

    const int tid = threadIdx.x;
    const int lane = tid & 63;
    const int w = tid >> 6;
    const int wr = (w / WAVES_N) * WTM;
    const int wc = (w % WAVES_N) * 64;
    const int fr = lane & 15;        // fragment row (A) / col (B)
    const int fk = (lane >> 4) * 8;  // fragment k offset (8 bf16)

    // ---- bijective XCD-chunked, m-fastest block remap ----
    const int nwg = gridDim.x * gridDim.y;
    const int lin = blockIdx.y * gridDim.x + blockIdx.x;
    const int q8 = nwg >> 3, r8 = nwg & 7;
    const int xcd = lin & 7, pos = lin >> 3;
    const int wg = (xcd < r8 ? xcd * (q8 + 1) : r8 * (q8 + 1) + (xcd - r8) * q8) + pos;
    const int MB = gridDim.y;                 // number of m-blocks
    const int bm = (wg % MB) * BM;
    const int bn = (wg / MB) * BN;

    const u16* A = Ag + (long)blockIdx.z * sA;
    const u16* B = Bg + (long)blockIdx.z * sB;

    f32x4 acc[MF][4] = {};

    for (int k0 = 0; k0 < K; k0 += 32) {
        // ---- stage A tile: BM rows x 32 k (4 chunks of 8 bf16) ----
        #pragma unroll
        for (int p = 0; p < BM / 64; ++p) {
            int idx = p * 256 + tid;
            int r = idx >> 2, c = idx & 3;
            *reinterpret_cast<float4*>(&As[r][c * 8]) =
                *reinterpret_cast<const float4*>(&A[(long)(bm + r) * lda + k0 + c * 8]);
        }
        // ---- stage B tile ----
        #pragma unroll
        for (int p = 0; p < BN / 64; ++p) {
            int idx = p * 256 + tid;
            int r = idx >> 2, c = idx & 3;
            *reinterpret_cast<float4*>(&Bs[r][c * 8]) =
                *reinterpret_cast<const float4*>(&B[(long)(bn + r) * ldb + k0 + c * 8]);
        }
        __syncthreads();

        bf16x8 a[MF], b[4];
        #pragma unroll
        for (int i = 0; i < MF; ++i)
            a[i] = *reinterpret_cast<const bf16x8*>(&As[wr + i * 16 + fr][fk]);
        #pragma unroll
        for (int j = 0; j < 4; ++j)
            b[j] = *reinterpret_cast<const bf16x8*>(&Bs[wc + j * 16 + fr][fk]);
        #pragma unroll
        for (int i = 0; i < MF; ++i)
            #pragma unroll
            for (int j = 0; j < 4; ++j)
                acc[i][j] = __builtin_amdgcn_mfma_f32_16x16x32_bf16(a[i], b[j], acc[i][j], 0, 0, 0);
        __syncthreads();
    }

    float* Cf = Cfg ? Cfg + (long)blockIdx.z * sC : nullptr;
    u16*   Cb = Cbg ? Cbg + (long)blockIdx.z * sC : nullptr;
    const int cr = (lane >> 4) * 4;
    #pragma unroll
    for (int i = 0; i < MF; ++i) {
        #pragma unroll
        for (int j = 0; j < 4; ++j) {
            int col = bn + wc + j * 16 + (lane & 15);
            #pragma unroll
            for (int r = 0; r < 4; ++r) {
                int row = bm + wr + i * 16 + cr + r;
                float v = acc[i][j][r] * scale;
                if (bias) v += bias[col];
                if (cadd) v += cadd[(long)row * ldc + col];
                if (relu) v = fmaxf(v, 0.0f);
                long o = (long)row * ldc + col;
                if (Cf) Cf[o] = v;
                if (Cb) Cb[o] = f2bf(v);
            }
        }
    }
}

// fp32 [R][C] -> bf16 [C][R], tiled transpose+convert (coalesced both sides)
__global__ __launch_bounds__(256) void transcvt_k(
    const float* __restrict__ in, u16* __restrict__ out, int R, int C)
{
    __shared__ float t[32][33];
    int tx = threadIdx.x & 31, ty = threadIdx.x >> 5;
    long r0 = (long)blockIdx.y * 32, c0 = (long)blockIdx.x * 32;
    #pragma unroll
    for (int i = 0; i < 32; i += 8)
        t[ty + i][tx] = in[(r0 + ty + i) * C + c0 + tx];
    __syncthreads();
    #pragma unroll
    for (int i = 0; i < 32; i += 8)
        out[(c0 + ty + i) * R + r0 + tx] = f2bf(t[tx][ty + i]);
}

// per-batch bf16 transpose: out[b][d][s] = in[b][s][d]
__global__ __launch_bounds__(256) void vtrans_k(
    const u16* __restrict__ in, u16* __restrict__ out)
{
    __shared__ u16 t[32][33];
    int tx = threadIdx.x & 31, ty = threadIdx.x >> 5;  // ty in 0..7
    int s0 = blockIdx.x * 32, d0 = blockIdx.y * 32;
    const u16* ib = in + (long)blockIdx.z * SEQ * HID;
    u16* ob = out + (long)blockIdx.z * HID * SEQ;
    #pragma unroll
    for (int i = 0; i < 32; i += 8)
        t[ty + i][tx] = ib[(long)(s0 + ty + i) * HID + d0 + tx];
    __syncthreads();
    #pragma unroll
    for (int i = 0; i < 32; i += 8)
        ob[(long)(d0 + ty + i) * SEQ + s0 + tx] = t[tx][ty + i];
}

// x[b,s,e] = tok_embed[tokens[b,s], e] + pos_embed[s, e]; fp32 + bf16 copies
__global__ __launch_bounds__(256) void embed_k(
    const int* __restrict__ tokens, const float* __restrict__ tok_embed,
    const float* __restrict__ pos_embed, float* __restrict__ x, u16* __restrict__ xb)
{
    long i = (long)blockIdx.x * 256 + threadIdx.x;
    long se = i / EDIM;
    int e = (int)(i % EDIM);
    int s = (int)(se % SEQ);
    int t = tokens[se];
    float v = tok_embed[(long)t * EDIM + e] + pos_embed[(long)s * EDIM + e];
    x[i] = v;
    xb[i] = f2bf(v);
}

// ---- 2-phase column softmax over t for scoresT[h][t][s] (UNMASKED, bug-faithful) ----
// phase 1: per (h, t-chunk, s) online max/sum partials.
__global__ __launch_bounds__(256) void colsm_stats(
    const float* __restrict__ sT, float* __restrict__ stats)
{
    int s = blockIdx.x * 256 + threadIdx.x;
    int tc = blockIdx.y, h = blockIdx.z;
    const float* p = sT + (long)h * SEQ * SEQ;
    float m = -1e30f, sum = 0.0f;
    for (int t = tc * (SEQ / TC); t < (tc + 1) * (SEQ / TC); ++t) {
        float v = p[(long)t * SEQ + s];
        float nm = fmaxf(m, v);
        sum = sum * __expf(m - nm) + __expf(v - nm);
        m = nm;
    }
    float* st = stats + (long)(h * TC + tc) * 2 * SEQ;
    st[s] = m;
    st[SEQ + s] = sum;
}

// phase 2: combine TC partials per column, then write bf16 probs for own t-chunk.
__global__ __launch_bounds__(256) void colsm_write(
    const float* __restrict__ sT, const float* __restrict__ stats,
    u16* __restrict__ pT)
{
    int s = blockIdx.x * 256 + threadIdx.x;
    int tc = blockIdx.y, h = blockIdx.z;
    float m = -1e30f, sum = 0.0f;
    for (int c = 0; c < TC; ++c) {
        const float* st = stats + (long)(h * TC + c) * 2 * SEQ;
        float mc = st[s], sc = st[SEQ + s];
        float nm = fmaxf(m, mc);
        sum = sum * __expf(m - nm) + sc * __expf(mc - nm);
        m = nm;
    }
    float inv = 1.0f / sum;
    const float* p = sT + (long)h * SEQ * SEQ;
    u16* o = pT + (long)h * SEQ * SEQ;
    for (int t = tc * (SEQ / TC); t < (tc + 1) * (SEQ / TC); ++t)
        o[(long)t * SEQ + s] = f2bf(__expf(p[(long)t * SEQ + s] - m) * inv);
}

// out(bf16) = rmsnorm(xin (+ add)) * scale ; add may be null
__global__ __launch_bounds__(256) void rmsnorm_k(
    const float* __restrict__ xin, const float* __restrict__ add,
    const float* __restrict__ scale, u16* __restrict__ out, int ncol)
{
    long row = blockIdx.x;
    const float* a = xin + row * (long)ncol;
    const float* b = add ? add + row * (long)ncol : nullptr;
    u16* o = out + row * (long)ncol;
    int tid = threadIdx.x;
    __shared__ float red[256];

    float ss = 0.0f;
    for (int c = tid; c < ncol; c += 256) { float v = a[c] + (b ? b[c] : 0.0f); ss += v * v; }
    red[tid] = ss; __syncthreads();
    for (int s = 128; s > 0; s >>= 1) { if (tid < s) red[tid] += red[tid + s]; __syncthreads(); }
    float r = rsqrtf(red[0] / (float)ncol + 1e-6f);
    for (int c = tid; c < ncol; c += 256) {
        float v = a[c] + (b ? b[c] : 0.0f);
        o[c] = f2bf(v * r * scale[c]);
    }
}

// in-place log_softmax on fp32 rows
__global__ __launch_bounds__(256) void logsoftmax_k(float* __restrict__ out, int ncol)
{
    long row = blockIdx.x;
    float* p = out + row * (long)ncol;
    int tid = threadIdx.x;
    __shared__ float red[256];

    float lmax = -1e30f;
    for (int c = tid; c < ncol; c += 256) lmax = fmaxf(lmax, p[c]);
    red[tid] = lmax; __syncthreads();
    for (int s = 128; s > 0; s >>= 1) { if (tid < s) red[tid] = fmaxf(red[tid], red[tid + s]); __syncthreads(); }
    float m = red[0]; __syncthreads();

    float lsum = 0.0f;
    for (int c = tid; c < ncol; c += 256) lsum += expf(p[c] - m);
    red[tid] = lsum; __syncthreads();
    for (int s = 128; s > 0; s >>= 1) { if (tid < s) red[tid] += red[tid + s]; __syncthreads(); }
    float lse = m + logf(red[0]);
    for (int c = tid; c < ncol; c += 256) p[c] = p[c] - lse;
}

extern "C" void kernel_launch(void* const* d_in, const int* in_sizes, int n_in,
                              void* d_out, int out_size, void* d_ws, size_t ws_size,
                              hipStream_t stream)
{
    const int*   tokens     = (const int*)d_in[0];
    const float* tok_embed  = (const float*)d_in[1];
    const float* pos_embed  = (const float*)d_in[2];
    const float* Qw_all     = (const float*)d_in[3];
    const float* Kw_all     = (const float*)d_in[4];
    const float* Vw_all     = (const float*)d_in[5];
    const float* Ow_all     = (const float*)d_in[6];
    const float* rms2_all   = (const float*)d_in[7];
    const float* w1_all     = (const float*)d_in[8];
    const float* b1_all     = (const float*)d_in[9];
    const float* w2_all     = (const float*)d_in[10];
    const float* b2_all     = (const float*)d_in[11];
    const float* final_rms  = (const float*)d_in[12];
    const float* w_out      = (const float*)d_in[13];
    const float* b_out      = (const float*)d_in[14];
    float* out = (float*)d_out;

    // workspace layout — 80 MB peak (footprint proven by the original session)
    if (ws_size < ((size_t)80 << 20)) return;   // graceful fail -> diagnostics survive
    char* W = (char*)d_ws;
    float* x    = (float*)(W + ((long)0  << 20));   // 8 MB  fp32 residual
    float* proj = (float*)(W + ((long)8  << 20));   // 8 MB  fp32 (live attn-end..FFN2)
    u16* xb   = (u16*)(W + ((long)16 << 20));       // 4 MB  bf16 copy of x
    u16* q    = (u16*)(W + ((long)20 << 20));       // 4 MB
    u16* kk   = (u16*)(W + ((long)24 << 20));       // 4 MB
    u16* vt   = (u16*)(W + ((long)28 << 20));       // 4 MB  v transposed [b][hid][s]
    u16* mha  = (u16*)(W + ((long)32 << 20));       // 4 MB
    u16* rn   = (u16*)(W + ((long)36 << 20));       // 4 MB
    u16* ffh  = (u16*)(W + ((long)40 << 20));       // 16 MB FFN hidden; sT aliases
    u16* wstage = (u16*)(W + ((long)56 << 20));     // 8 MB  per-weight bf16 staging (reused 6x/layer)
    float* smstats = (float*)(W + ((long)64 << 20));// 256 KB softmax partials
    // aliases with disjoint lifetimes:
    u16* vv   = (u16*)proj;                         // 4 MB  v un-transposed (pre-attention; proj dead)
    float* sT = (float*)ffh;                        // 16 MB scoresT chunk (4 heads, fp32)
    u16* pT   = (u16*)proj;                         // 8 MB probsT chunk (attention; proj dead)
    // endgame (layer buffers dead): final rn + staged w_out
    u16* rnF  = (u16*)(W + ((long)76 << 20));       // 4 MB
    u16* woT  = (u16*)(W + ((long)8  << 20));       // 65.5 MB (8..73.5), aliases all but x/rnF

    // 1) embedding (fp32 + bf16)
    embed_k<<<(NTOK * (long)EDIM) / 256, 256, 0, stream>>>(tokens, tok_embed, pos_embed, x, xb);

    for (int l = 0; l < LNUM; ++l) {
        const float* Qw  = Qw_all + (long)l * EDIM * HID;
        const float* Kw  = Kw_all + (long)l * EDIM * HID;
        const float* Vw  = Vw_all + (long)l * EDIM * HID;
        const float* Ow  = Ow_all + (long)l * HID * EDIM;
        const float* rs2 = rms2_all + (long)l * EDIM;
        const float* w1  = w1_all + (long)l * EDIM * 4 * EDIM;
        const float* b1  = b1_all + (long)l * 4 * EDIM;
        const float* w2  = w2_all + (long)l * 4 * EDIM * EDIM;
        const float* b2  = b2_all + (long)l * EDIM;

        // q/k/v projections: stage weight -> fast bf16 GEMM (stage region reused)
        transcvt_k<<<dim3(HID / 32, EDIM / 32), 256, 0, stream>>>(Qw, wstage, EDIM, HID);
        bgemm<128, 128><<<dim3(HID / 128, NTOK / 128, 1), 256, 0, stream>>>(
            xb, wstage, nullptr, q, NTOK, HID, EDIM, EDIM, EDIM, HID, 0, 0, 0, 1.0f, nullptr, nullptr, 0);
        transcvt_k<<<dim3(HID / 32, EDIM / 32), 256, 0, stream>>>(Kw, wstage, EDIM, HID);
        bgemm<128, 128><<<dim3(HID / 128, NTOK / 128, 1), 256, 0, stream>>>(
            xb, wstage, nullptr, kk, NTOK, HID, EDIM, EDIM, EDIM, HID, 0, 0, 0, 1.0f, nullptr, nullptr, 0);
        transcvt_k<<<dim3(HID / 32, EDIM / 32), 256, 0, stream>>>(Vw, wstage, EDIM, HID);
        bgemm<128, 128><<<dim3(HID / 128, NTOK / 128, 1), 256, 0, stream>>>(
            xb, wstage, nullptr, vv, NTOK, HID, EDIM, EDIM, EDIM, HID, 0, 0, 0, 1.0f, nullptr, nullptr, 0);
        // vt[b][d][s] = vv[b][s][d]
        vtrans_k<<<dim3(SEQ / 32, HID / 32, BATCH), 256, 0, stream>>>(vv, vt);

        for (int b = 0; b < BATCH; ++b) {
            const u16* qb = q  + (long)b * SEQ * HID;
            const u16* kb = kk + (long)b * SEQ * HID;
            for (int h0 = 0; h0 < NH; h0 += HCHUNK) {
                // scoresT[h][t][s] = 0.125 * k_t . q_s  (z over heads)
                bgemm<128, 128><<<dim3(SEQ / 128, SEQ / 128, HCHUNK), 256, 0, stream>>>(
                    kb + h0 * HD, qb + h0 * HD, sT, nullptr, SEQ, SEQ, HD, HID, HID, SEQ,
                    HD, HD, (long)SEQ * SEQ, 0.125f, nullptr, nullptr, 0);
                // 2-phase column softmax -> bf16 probsT
                colsm_stats<<<dim3(SEQ / 256, TC, HCHUNK), 256, 0, stream>>>(sT, smstats);
                colsm_write<<<dim3(SEQ / 256, TC, HCHUNK), 256, 0, stream>>>(sT, smstats, pT);
                // mha[t][(h0+h)*HD+d] = sum_s probsT[h][t][s] * vt[b][(h0+h)*HD+d][s]
                bgemm<64, 64><<<dim3(1, SEQ / 64, HCHUNK), 256, 0, stream>>>(
                    pT, vt + (long)b * HID * SEQ + (long)h0 * HD * SEQ, nullptr,
                    mha + (long)b * SEQ * HID + h0 * HD,
                    SEQ, HD, SEQ, SEQ, SEQ, HID,
                    (long)SEQ * SEQ, (long)HD * SEQ, HD, 1.0f, nullptr, nullptr, 0);
            }
        }

        // proj = mha @ Ow  (fp32 out)
        transcvt_k<<<dim3(EDIM / 32, HID / 32), 256, 0, stream>>>(Ow, wstage, HID, EDIM);
        bgemm<128, 128><<<dim3(EDIM / 128, NTOK / 128, 1), 256, 0, stream>>>(
            mha, wstage, proj, nullptr, NTOK, EDIM, HID, HID, HID, EDIM, 0, 0, 0, 1.0f, nullptr, nullptr, 0);

        // rn = bf16(rmsnorm(x + proj) * rs2)
        rmsnorm_k<<<NTOK, 256, 0, stream>>>(x, proj, rs2, rn, EDIM);

        // ffh = bf16(relu(rn @ w1 + b1))
        transcvt_k<<<dim3(4 * EDIM / 32, EDIM / 32), 256, 0, stream>>>(w1, wstage, EDIM, 4 * EDIM);
        bgemm<128, 128><<<dim3(4 * EDIM / 128, NTOK / 128, 1), 256, 0, stream>>>(
            rn, wstage, nullptr, ffh, NTOK, 4 * EDIM, EDIM, EDIM, EDIM, 4 * EDIM,
            0, 0, 0, 1.0f, b1, nullptr, 1);

        // x = ffh @ w2 + b2 + proj  (fp32 x AND bf16 xb; input x NOT re-added — bug-faithful)
        transcvt_k<<<dim3(EDIM / 32, 4 * EDIM / 32), 256, 0, stream>>>(w2, wstage, 4 * EDIM, EDIM);
        bgemm<128, 128><<<dim3(EDIM / 128, NTOK / 128, 1), 256, 0, stream>>>(
            ffh, wstage, x, xb, NTOK, EDIM, 4 * EDIM, 4 * EDIM, 4 * EDIM, EDIM,
            0, 0, 0, 1.0f, b2, proj, 0);
    }

    // final rmsnorm -> bf16 (rnF placed outside woT's range)
    rmsnorm_k<<<NTOK, 256, 0, stream>>>(x, nullptr, final_rms, rnF, EDIM);

    // stage w_out (all layer buffers dead now), then logits GEMM
    transcvt_k<<<dim3(VOC / 32, EDIM / 32), 256, 0, stream>>>(w_out, woT, EDIM, VOC);
    bgemm<128, 128><<<dim3(VOC / 128, NTOK / 128, 1), 256, 0, stream>>>(
        rnF, woT, out, nullptr, NTOK, VOC, EDIM, EDIM, EDIM, VOC,
        0, 0, 0, 1.0f, b_out, nullptr, 0);

    logsoftmax_k<<<NTOK, 256, 0, stream>>>(out, VOC);
}

// Round 6
// 2208.832 us; speedup vs baseline: 3.8083x; 2.4363x over previous
//
#include <hip/hip_runtime.h>

// Problem constants
#define LNUM 4
#define EDIM 1024
#define HID 1024
#define NH 16
#define HD 64
#define VOC 32000
#define SEQ 1024
#define BATCH 2
#define NTOK (BATCH * SEQ)   // 2048

typedef unsigned short u16;
typedef short bf16x8 __attribute__((ext_vector_type(8)));   // 8 bf16 in 4 VGPRs
typedef float f32x4 __attribute__((ext_vector_type(4)));

__device__ __forceinline__ u16 f2bf(float f) {
    union { float f; unsigned u; } c; c.f = f;
    return (u16)((c.u + 0x7fffu + ((c.u >> 16) & 1u)) >> 16);  // RNE
}

// -----------------------------------------------------------------------------
// bf16 MFMA GEMM, TN compute:
//   C[m,n] = scale * sum_k A(m,k)*B(n,k)  (+bias[n]) (+cadd[m,n]) (relu?)
// A: bf16 [M][K] row-major (lda). B: bf16 [N][K] row-major (ldb).
// Tile: BM x BN, BK=32, 256 threads = 4 waves. (BM,BN) in {(128,128),(64,128)}.
// LDS rows padded to 40 shorts: worst 2-way bank aliasing (free, m136).
// Block remap: bijective XCD chunking + m-fastest order (L2 B-panel reuse).
// -----------------------------------------------------------------------------
template <int BM, int BN>
__global__ __launch_bounds__(256) void bgemm(
    const u16* __restrict__ Ag, const u16* __restrict__ Bg,
    float* __restrict__ Cfg, u16* __restrict__ Cbg,
    int M, int N, int K, int lda, int ldb, int ldc,
    long sA, long sB, long sC, float scale,
    const float* __restrict__ bias, const float* __restrict__ cadd, int relu)
{
    constexpr int WAVES_N = BN / 64;
    constexpr int WAVES_M = 4 / WAVES_N;
    constexpr int WTM = BM / WAVES_M;
    constexpr int MF = WTM / 16;

    __shared__ u16 As[BM][40];
    __shared__ u16 Bs[BN][40];

    const int tid = threadIdx.x;
    const int lane = tid & 63;
    const int w = tid >> 6;
    const int wr = (w / WAVES_N) * WTM;
    const int wc = (w % WAVES_N) * 64;
    const int fr = lane & 15;
    const int fk = (lane >> 4) * 8;

    const int nwg = gridDim.x * gridDim.y;
    const int lin = blockIdx.y * gridDim.x + blockIdx.x;
    const int q8 = nwg >> 3, r8 = nwg & 7;
    const int xcd = lin & 7, pos = lin >> 3;
    const int wg = (xcd < r8 ? xcd * (q8 + 1) : r8 * (q8 + 1) + (xcd - r8) * q8) + pos;
    const int MB = gridDim.y;
    const int bm = (wg % MB) * BM;
    const int bn = (wg / MB) * BN;

    const u16* A = Ag + (long)blockIdx.z * sA;
    const u16* B = Bg + (long)blockIdx.z * sB;

    f32x4 acc[MF][4] = {};

    for (int k0 = 0; k0 < K; k0 += 32) {
        #pragma unroll
        for (int p = 0; p < BM / 64; ++p) {
            int idx = p * 256 + tid;
            int r = idx >> 2, c = idx & 3;
            *reinterpret_cast<float4*>(&As[r][c * 8]) =
                *reinterpret_cast<const float4*>(&A[(long)(bm + r) * lda + k0 + c * 8]);
        }
        #pragma unroll
        for (int p = 0; p < BN / 64; ++p) {
            int idx = p * 256 + tid;
            int r = idx >> 2, c = idx & 3;
            *reinterpret_cast<float4*>(&Bs[r][c * 8]) =
                *reinterpret_cast<const float4*>(&B[(long)(bn + r) * ldb + k0 + c * 8]);
        }
        __syncthreads();

        bf16x8 a[MF], b[4];
        #pragma unroll
        for (int i = 0; i < MF; ++i)
            a[i] = *reinterpret_cast<const bf16x8*>(&As[wr + i * 16 + fr][fk]);
        #pragma unroll
        for (int j = 0; j < 4; ++j)
            b[j] = *reinterpret_cast<const bf16x8*>(&Bs[wc + j * 16 + fr][fk]);
        #pragma unroll
        for (int i = 0; i < MF; ++i)
            #pragma unroll
            for (int j = 0; j < 4; ++j)
                acc[i][j] = __builtin_amdgcn_mfma_f32_16x16x32_bf16(a[i], b[j], acc[i][j], 0, 0, 0);
        __syncthreads();
    }

    float* Cf = Cfg ? Cfg + (long)blockIdx.z * sC : nullptr;
    u16*   Cb = Cbg ? Cbg + (long)blockIdx.z * sC : nullptr;
    const int cr = (lane >> 4) * 4;
    #pragma unroll
    for (int i = 0; i < MF; ++i) {
        #pragma unroll
        for (int j = 0; j < 4; ++j) {
            int col = bn + wc + j * 16 + (lane & 15);
            #pragma unroll
            for (int r = 0; r < 4; ++r) {
                int row = bm + wr + i * 16 + cr + r;
                float v = acc[i][j][r] * scale;
                if (bias) v += bias[col];
                if (cadd) v += cadd[(long)row * ldc + col];
                if (relu) v = fmaxf(v, 0.0f);
                long o = (long)row * ldc + col;
                if (Cf) Cf[o] = v;
                if (Cb) Cb[o] = f2bf(v);
            }
        }
    }
}

// -----------------------------------------------------------------------------
// Fused attention, pass 1: softmax-over-t stats per s-row (UNMASKED, bug-faithful).
// grid (SEQ/128, NH, BATCH). Block: 128 s-rows, stream K in 128-t tiles.
// stats[(b*NH+h)*2*SEQ + s] = m_s ; [... + SEQ + s] = 1/Z_s.
// -----------------------------------------------------------------------------
__global__ __launch_bounds__(256) void attn_stats(
    const u16* __restrict__ q, const u16* __restrict__ kk, float* __restrict__ stats)
{
    const int b = blockIdx.z, h = blockIdx.y, s0 = blockIdx.x * 128;
    const u16* qb = q  + (long)b * SEQ * HID + h * HD;
    const u16* kb = kk + (long)b * SEQ * HID + h * HD;

    __shared__ u16 Qs[128][72];
    __shared__ u16 Ks[128][72];

    const int tid = threadIdx.x;
    const int lane = tid & 63;
    const int w = tid >> 6;
    const int wr = w * 32;           // 32 s-rows per wave
    const int fr = lane & 15;
    const int fk = (lane >> 4) * 8;
    const int cr = (lane >> 4) * 4;

    // stage Q tile (128 x 64)
    #pragma unroll
    for (int p = 0; p < 4; ++p) {
        int idx = p * 256 + tid;
        int r = idx >> 3, c = idx & 7;
        *reinterpret_cast<float4*>(&Qs[r][c * 8]) =
            *reinterpret_cast<const float4*>(&qb[(long)(s0 + r) * HID + c * 8]);
    }

    float m_[2][4], Z_[2][4];
    #pragma unroll
    for (int i = 0; i < 2; ++i)
        #pragma unroll
        for (int r = 0; r < 4; ++r) { m_[i][r] = -1e30f; Z_[i][r] = 0.0f; }

    for (int t0 = 0; t0 < SEQ; t0 += 128) {
        #pragma unroll
        for (int p = 0; p < 4; ++p) {
            int idx = p * 256 + tid;
            int r = idx >> 3, c = idx & 7;
            *reinterpret_cast<float4*>(&Ks[r][c * 8]) =
                *reinterpret_cast<const float4*>(&kb[(long)(t0 + r) * HID + c * 8]);
        }
        __syncthreads();

        f32x4 acc[2][8] = {};
        #pragma unroll
        for (int ks = 0; ks < 2; ++ks) {
            bf16x8 a[2], bfr[8];
            #pragma unroll
            for (int i = 0; i < 2; ++i)
                a[i] = *reinterpret_cast<const bf16x8*>(&Qs[wr + i * 16 + fr][ks * 32 + fk]);
            #pragma unroll
            for (int j = 0; j < 8; ++j)
                bfr[j] = *reinterpret_cast<const bf16x8*>(&Ks[j * 16 + fr][ks * 32 + fk]);
            #pragma unroll
            for (int i = 0; i < 2; ++i)
                #pragma unroll
                for (int j = 0; j < 8; ++j)
                    acc[i][j] = __builtin_amdgcn_mfma_f32_16x16x32_bf16(a[i], bfr[j], acc[i][j], 0, 0, 0);
        }

        // online stats update per row
        #pragma unroll
        for (int i = 0; i < 2; ++i) {
            #pragma unroll
            for (int r = 0; r < 4; ++r) {
                float tm = -1e30f;
                #pragma unroll
                for (int j = 0; j < 8; ++j) tm = fmaxf(tm, acc[i][j][r] * 0.125f);
                #pragma unroll
                for (int msk = 1; msk < 16; msk <<= 1) tm = fmaxf(tm, __shfl_xor(tm, msk));
                float nm = fmaxf(m_[i][r], tm);
                float ps = 0.0f;
                #pragma unroll
                for (int j = 0; j < 8; ++j) ps += __expf(acc[i][j][r] * 0.125f - nm);
                #pragma unroll
                for (int msk = 1; msk < 16; msk <<= 1) ps += __shfl_xor(ps, msk);
                Z_[i][r] = Z_[i][r] * __expf(m_[i][r] - nm) + ps;
                m_[i][r] = nm;
            }
        }
        __syncthreads();
    }

    float* st = stats + ((long)(b * NH + h) * 2) * SEQ;
    if ((lane & 15) == 0) {
        #pragma unroll
        for (int i = 0; i < 2; ++i)
            #pragma unroll
            for (int r = 0; r < 4; ++r) {
                int s = s0 + wr + i * 16 + cr + r;
                st[s] = m_[i][r];
                st[SEQ + s] = 1.0f / Z_[i][r];
            }
    }
}

// -----------------------------------------------------------------------------
// Fused attention, pass 2: out[t][d] = sum_s exp(0.125*k_t.q_s - m_s)/Z_s * v[s][d]
// grid (SEQ/128, NH, BATCH). Block: 128 t-rows, loop s-tiles of 64.
// Recomputes scores via MFMA; P rounded to bf16 in LDS; PV via MFMA (vt operand).
// -----------------------------------------------------------------------------
__global__ __launch_bounds__(256) void attn_pv(
    const u16* __restrict__ q, const u16* __restrict__ kk, const u16* __restrict__ vt,
    const float* __restrict__ stats, u16* __restrict__ mha)
{
    const int b = blockIdx.z, h = blockIdx.y, t0 = blockIdx.x * 128;
    const u16* qb = q  + (long)b * SEQ * HID + h * HD;
    const u16* kb = kk + (long)b * SEQ * HID + h * HD;
    const u16* vb = vt + ((long)b * HID + h * HD) * SEQ;
    const float* st = stats + ((long)(b * NH + h) * 2) * SEQ;

    __shared__ u16 Ks[128][72];  // A rows t (k-dim d=64)
    __shared__ u16 Qs[64][72];   // B rows s (k-dim d=64)
    __shared__ u16 Vs[64][72];   // B rows d (k-dim s=64)
    __shared__ u16 Ps[128][72];  // A rows t (k-dim s=64), bf16 probs

    const int tid = threadIdx.x;
    const int lane = tid & 63;
    const int w = tid >> 6;
    const int wr = w * 32;           // 32 t-rows per wave
    const int fr = lane & 15;
    const int fk = (lane >> 4) * 8;
    const int cr = (lane >> 4) * 4;

    // stage K tile (block's 128 t-rows)
    #pragma unroll
    for (int p = 0; p < 4; ++p) {
        int idx = p * 256 + tid;
        int r = idx >> 3, c = idx & 7;
        *reinterpret_cast<float4*>(&Ks[r][c * 8]) =
            *reinterpret_cast<const float4*>(&kb[(long)(t0 + r) * HID + c * 8]);
    }
    __syncthreads();

    f32x4 accO[2][4] = {};

    for (int s0 = 0; s0 < SEQ; s0 += 64) {
        // stage Q s-tile (64 x 64) and V tile (64 d x 64 s)
        #pragma unroll
        for (int p = 0; p < 2; ++p) {
            int idx = p * 256 + tid;
            int r = idx >> 3, c = idx & 7;
            *reinterpret_cast<float4*>(&Qs[r][c * 8]) =
                *reinterpret_cast<const float4*>(&qb[(long)(s0 + r) * HID + c * 8]);
        }
        #pragma unroll
        for (int p = 0; p < 2; ++p) {
            int idx = p * 256 + tid;
            int r = idx >> 3, c = idx & 7;
            *reinterpret_cast<float4*>(&Vs[r][c * 8]) =
                *reinterpret_cast<const float4*>(&vb[(long)r * SEQ + s0 + c * 8]);
        }
        __syncthreads();

        // scores: acc2[t-frag][s-frag] = k_t . q_s
        f32x4 acc2[2][4] = {};
        #pragma unroll
        for (int ks = 0; ks < 2; ++ks) {
            bf16x8 a[2], bfr[4];
            #pragma unroll
            for (int i = 0; i < 2; ++i)
                a[i] = *reinterpret_cast<const bf16x8*>(&Ks[wr + i * 16 + fr][ks * 32 + fk]);
            #pragma unroll
            for (int j = 0; j < 4; ++j)
                bfr[j] = *reinterpret_cast<const bf16x8*>(&Qs[j * 16 + fr][ks * 32 + fk]);
            #pragma unroll
            for (int i = 0; i < 2; ++i)
                #pragma unroll
                for (int j = 0; j < 4; ++j)
                    acc2[i][j] = __builtin_amdgcn_mfma_f32_16x16x32_bf16(a[i], bfr[j], acc2[i][j], 0, 0, 0);
        }

        // weights -> bf16 P-tile in LDS
        float mld[4], ild[4];
        #pragma unroll
        for (int j = 0; j < 4; ++j) {
            int sg = s0 + j * 16 + (lane & 15);
            mld[j] = st[sg];
            ild[j] = st[SEQ + sg];
        }
        #pragma unroll
        for (int i = 0; i < 2; ++i)
            #pragma unroll
            for (int j = 0; j < 4; ++j)
                #pragma unroll
                for (int r = 0; r < 4; ++r) {
                    float wv = __expf(acc2[i][j][r] * 0.125f - mld[j]) * ild[j];
                    Ps[wr + i * 16 + cr + r][j * 16 + (lane & 15)] = f2bf(wv);
                }
        __syncthreads();

        // PV: accO[t-frag][d-frag] += P[t][s] * V[d][s]
        #pragma unroll
        for (int ks = 0; ks < 2; ++ks) {
            bf16x8 a[2], bfr[4];
            #pragma unroll
            for (int i = 0; i < 2; ++i)
                a[i] = *reinterpret_cast<const bf16x8*>(&Ps[wr + i * 16 + fr][ks * 32 + fk]);
            #pragma unroll
            for (int j = 0; j < 4; ++j)
                bfr[j] = *reinterpret_cast<const bf16x8*>(&Vs[j * 16 + fr][ks * 32 + fk]);
            #pragma unroll
            for (int i = 0; i < 2; ++i)
                #pragma unroll
                for (int j = 0; j < 4; ++j)
                    accO[i][j] = __builtin_amdgcn_mfma_f32_16x16x32_bf16(a[i], bfr[j], accO[i][j], 0, 0, 0);
        }
        __syncthreads();
    }

    u16* mhab = mha + (long)b * SEQ * HID;
    #pragma unroll
    for (int i = 0; i < 2; ++i)
        #pragma unroll
        for (int j = 0; j < 4; ++j) {
            int d = j * 16 + (lane & 15);
            #pragma unroll
            for (int r = 0; r < 4; ++r) {
                int t = t0 + wr + i * 16 + cr + r;
                mhab[(long)t * HID + h * HD + d] = f2bf(accO[i][j][r]);
            }
        }
}

// fp32 [R][C] -> bf16 [C][R], tiled transpose+convert
__global__ __launch_bounds__(256) void transcvt_k(
    const float* __restrict__ in, u16* __restrict__ out, int R, int C)
{
    __shared__ float t[32][33];
    int tx = threadIdx.x & 31, ty = threadIdx.x >> 5;
    long r0 = (long)blockIdx.y * 32, c0 = (long)blockIdx.x * 32;
    #pragma unroll
    for (int i = 0; i < 32; i += 8)
        t[ty + i][tx] = in[(r0 + ty + i) * C + c0 + tx];
    __syncthreads();
    #pragma unroll
    for (int i = 0; i < 32; i += 8)
        out[(c0 + ty + i) * R + r0 + tx] = f2bf(t[tx][ty + i]);
}

// per-batch bf16 transpose: out[b][d][s] = in[b][s][d]
__global__ __launch_bounds__(256) void vtrans_k(
    const u16* __restrict__ in, u16* __restrict__ out)
{
    __shared__ u16 t[32][33];
    int tx = threadIdx.x & 31, ty = threadIdx.x >> 5;
    int s0 = blockIdx.x * 32, d0 = blockIdx.y * 32;
    const u16* ib = in + (long)blockIdx.z * SEQ * HID;
    u16* ob = out + (long)blockIdx.z * HID * SEQ;
    #pragma unroll
    for (int i = 0; i < 32; i += 8)
        t[ty + i][tx] = ib[(long)(s0 + ty + i) * HID + d0 + tx];
    __syncthreads();
    #pragma unroll
    for (int i = 0; i < 32; i += 8)
        ob[(long)(d0 + ty + i) * SEQ + s0 + tx] = t[tx][ty + i];
}

// x[b,s,e] = tok_embed[tokens[b,s], e] + pos_embed[s, e]; fp32 + bf16 copies
__global__ __launch_bounds__(256) void embed_k(
    const int* __restrict__ tokens, const float* __restrict__ tok_embed,
    const float* __restrict__ pos_embed, float* __restrict__ x, u16* __restrict__ xb)
{
    long i = (long)blockIdx.x * 256 + threadIdx.x;
    long se = i / EDIM;
    int e = (int)(i % EDIM);
    int s = (int)(se % SEQ);
    int t = tokens[se];
    float v = tok_embed[(long)t * EDIM + e] + pos_embed[(long)s * EDIM + e];
    x[i] = v;
    xb[i] = f2bf(v);
}

// out(bf16) = rmsnorm(xin (+ add)) * scale ; add may be null
__global__ __launch_bounds__(256) void rmsnorm_k(
    const float* __restrict__ xin, const float* __restrict__ add,
    const float* __restrict__ scale, u16* __restrict__ out, int ncol)
{
    long row = blockIdx.x;
    const float* a = xin + row * (long)ncol;
    const float* b = add ? add + row * (long)ncol : nullptr;
    u16* o = out + row * (long)ncol;
    int tid = threadIdx.x;
    __shared__ float red[256];

    float ss = 0.0f;
    for (int c = tid; c < ncol; c += 256) { float v = a[c] + (b ? b[c] : 0.0f); ss += v * v; }
    red[tid] = ss; __syncthreads();
    for (int s = 128; s > 0; s >>= 1) { if (tid < s) red[tid] += red[tid + s]; __syncthreads(); }
    float r = rsqrtf(red[0] / (float)ncol + 1e-6f);
    for (int c = tid; c < ncol; c += 256) {
        float v = a[c] + (b ? b[c] : 0.0f);
        o[c] = f2bf(v * r * scale[c]);
    }
}

// in-place log_softmax on fp32 rows
__global__ __launch_bounds__(256) void logsoftmax_k(float* __restrict__ out, int ncol)
{
    long row = blockIdx.x;
    float* p = out + row * (long)ncol;
    int tid = threadIdx.x;
    __shared__ float red[256];

    float lmax = -1e30f;
    for (int c = tid; c < ncol; c += 256) lmax = fmaxf(lmax, p[c]);
    red[tid] = lmax; __syncthreads();
    for (int s = 128; s > 0; s >>= 1) { if (tid < s) red[tid] = fmaxf(red[tid], red[tid + s]); __syncthreads(); }
    float m = red[0]; __syncthreads();

    float lsum = 0.0f;
    for (int c = tid; c < ncol; c += 256) lsum += expf(p[c] - m);
    red[tid] = lsum; __syncthreads();
    for (int s = 128; s > 0; s >>= 1) { if (tid < s) red[tid] += red[tid + s]; __syncthreads(); }
    float lse = m + logf(red[0]);
    for (int c = tid; c < ncol; c += 256) p[c] = p[c] - lse;
}

extern "C" void kernel_launch(void* const* d_in, const int* in_sizes, int n_in,
                              void* d_out, int out_size, void* d_ws, size_t ws_size,
                              hipStream_t stream)
{
    const int*   tokens     = (const int*)d_in[0];
    const float* tok_embed  = (const float*)d_in[1];
    const float* pos_embed  = (const float*)d_in[2];
    const float* Qw_all     = (const float*)d_in[3];
    const float* Kw_all     = (const float*)d_in[4];
    const float* Vw_all     = (const float*)d_in[5];
    const float* Ow_all     = (const float*)d_in[6];
    const float* rms2_all   = (const float*)d_in[7];
    const float* w1_all     = (const float*)d_in[8];
    const float* b1_all     = (const float*)d_in[9];
    const float* w2_all     = (const float*)d_in[10];
    const float* b2_all     = (const float*)d_in[11];
    const float* final_rms  = (const float*)d_in[12];
    const float* w_out      = (const float*)d_in[13];
    const float* b_out      = (const float*)d_in[14];
    float* out = (float*)d_out;

    // workspace layout — 80 MB peak
    if (ws_size < ((size_t)80 << 20)) return;
    char* W = (char*)d_ws;
    float* x    = (float*)(W + ((long)0  << 20));   // 8 MB  fp32 residual
    float* proj = (float*)(W + ((long)8  << 20));   // 8 MB  fp32
    u16* xb   = (u16*)(W + ((long)16 << 20));       // 4 MB
    u16* q    = (u16*)(W + ((long)20 << 20));       // 4 MB
    u16* kk   = (u16*)(W + ((long)24 << 20));       // 4 MB
    u16* vt   = (u16*)(W + ((long)28 << 20));       // 4 MB  v transposed [b][hid][s]
    u16* mha  = (u16*)(W + ((long)32 << 20));       // 4 MB
    u16* rn   = (u16*)(W + ((long)36 << 20));       // 4 MB
    u16* ffh  = (u16*)(W + ((long)40 << 20));       // 16 MB FFN hidden
    u16* wstage = (u16*)(W + ((long)56 << 20));     // 8 MB  per-weight bf16 staging
    float* stats = (float*)(W + ((long)64 << 20));  // 256 KB attn softmax stats
    u16* vv   = (u16*)proj;                         // 4 MB  v un-transposed (proj dead then)
    // endgame
    u16* rnF  = (u16*)(W + ((long)76 << 20));       // 4 MB
    u16* woT  = (u16*)(W + ((long)8  << 20));       // 65.5 MB (aliases all but x/rnF)

    embed_k<<<(NTOK * (long)EDIM) / 256, 256, 0, stream>>>(tokens, tok_embed, pos_embed, x, xb);

    for (int l = 0; l < LNUM; ++l) {
        const float* Qw  = Qw_all + (long)l * EDIM * HID;
        const float* Kw  = Kw_all + (long)l * EDIM * HID;
        const float* Vw  = Vw_all + (long)l * EDIM * HID;
        const float* Ow  = Ow_all + (long)l * HID * EDIM;
        const float* rs2 = rms2_all + (long)l * EDIM;
        const float* w1  = w1_all + (long)l * EDIM * 4 * EDIM;
        const float* b1  = b1_all + (long)l * 4 * EDIM;
        const float* w2  = w2_all + (long)l * 4 * EDIM * EDIM;
        const float* b2  = b2_all + (long)l * EDIM;

        // q/k/v projections (64x128 tiles -> 256 blocks)
        transcvt_k<<<dim3(HID / 32, EDIM / 32), 256, 0, stream>>>(Qw, wstage, EDIM, HID);
        bgemm<64, 128><<<dim3(HID / 128, NTOK / 64, 1), 256, 0, stream>>>(
            xb, wstage, nullptr, q, NTOK, HID, EDIM, EDIM, EDIM, HID, 0, 0, 0, 1.0f, nullptr, nullptr, 0);
        transcvt_k<<<dim3(HID / 32, EDIM / 32), 256, 0, stream>>>(Kw, wstage, EDIM, HID);
        bgemm<64, 128><<<dim3(HID / 128, NTOK / 64, 1), 256, 0, stream>>>(
            xb, wstage, nullptr, kk, NTOK, HID, EDIM, EDIM, EDIM, HID, 0, 0, 0, 1.0f, nullptr, nullptr, 0);
        transcvt_k<<<dim3(HID / 32, EDIM / 32), 256, 0, stream>>>(Vw, wstage, EDIM, HID);
        bgemm<64, 128><<<dim3(HID / 128, NTOK / 64, 1), 256, 0, stream>>>(
            xb, wstage, nullptr, vv, NTOK, HID, EDIM, EDIM, EDIM, HID, 0, 0, 0, 1.0f, nullptr, nullptr, 0);
        vtrans_k<<<dim3(SEQ / 32, HID / 32, BATCH), 256, 0, stream>>>(vv, vt);

        // fused attention: stats pass + PV pass (1 launch each, all heads/batches)
        attn_stats<<<dim3(SEQ / 128, NH, BATCH), 256, 0, stream>>>(q, kk, stats);
        attn_pv<<<dim3(SEQ / 128, NH, BATCH), 256, 0, stream>>>(q, kk, vt, stats, mha);

        // proj = mha @ Ow
        transcvt_k<<<dim3(EDIM / 32, HID / 32), 256, 0, stream>>>(Ow, wstage, HID, EDIM);
        bgemm<64, 128><<<dim3(EDIM / 128, NTOK / 64, 1), 256, 0, stream>>>(
            mha, wstage, proj, nullptr, NTOK, EDIM, HID, HID, HID, EDIM, 0, 0, 0, 1.0f, nullptr, nullptr, 0);

        rmsnorm_k<<<NTOK, 256, 0, stream>>>(x, proj, rs2, rn, EDIM);

        // ffh = relu(rn @ w1 + b1)
        transcvt_k<<<dim3(4 * EDIM / 32, EDIM / 32), 256, 0, stream>>>(w1, wstage, EDIM, 4 * EDIM);
        bgemm<128, 128><<<dim3(4 * EDIM / 128, NTOK / 128, 1), 256, 0, stream>>>(
            rn, wstage, nullptr, ffh, NTOK, 4 * EDIM, EDIM, EDIM, EDIM, 4 * EDIM,
            0, 0, 0, 1.0f, b1, nullptr, 1);

        // x = ffh @ w2 + b2 + proj (bug-faithful)
        transcvt_k<<<dim3(EDIM / 32, 4 * EDIM / 32), 256, 0, stream>>>(w2, wstage, 4 * EDIM, EDIM);
        bgemm<64, 128><<<dim3(EDIM / 128, NTOK / 64, 1), 256, 0, stream>>>(
            ffh, wstage, x, xb, NTOK, EDIM, 4 * EDIM, 4 * EDIM, 4 * EDIM, EDIM,
            0, 0, 0, 1.0f, b2, proj, 0);
    }

    rmsnorm_k<<<NTOK, 256, 0, stream>>>(x, nullptr, final_rms, rnF, EDIM);

    transcvt_k<<<dim3(VOC / 32, EDIM / 32), 256, 0, stream>>>(w_out, woT, EDIM, VOC);
    bgemm<128, 128><<<dim3(VOC / 128, NTOK / 128, 1), 256, 0, stream>>>(
        rnF, woT, out, nullptr, NTOK, VOC, EDIM, EDIM, EDIM, VOC,
        0, 0, 0, 1.0f, b_out, nullptr, 0);

    logsoftmax_k<<<NTOK, 256, 0, stream>>>(out, VOC);
}